// Round 10
// baseline (476.048 us; speedup 1.0000x reference)
//
#include <hip/hip_runtime.h>
#include <hip/hip_fp16.h>
#include <math.h>

#define BATCH 8
#define H 480
#define W 640
#define HW (H * W)

// ---- single-launch geometry: all 16 steps fused ----
#define PS 16                 // fused steps (= total)
#define PTX 96                // output tile width
#define PTY 32                // output tile height
#define PRX 128               // region cols = PTX + 2*PS (= 64 lanes x 2)
#define PRY 64                // region rows = PTY + 2*PS
#define NT 1024               // 16 waves; wave = strip of 4 rows, lane = col-pair
#define RPT 4                 // rows per thread
#define NSTRIP 16

// DPP wave-wide shifts: lane i <- lane i-1 (0x138), lane i+1 (0x130).
// Shifted-in lanes take `old` (=0): region col -1 / col 128 read as 0 -> rim
// pixels only (trapezoid-stale-safe) or out-of-image pixels (w=0).
__device__ __forceinline__ float dppL(float v) {   // value from lane-1
    return __int_as_float(__builtin_amdgcn_update_dpp(
        0, __float_as_int(v), 0x138, 0xF, 0xF, false));
}
__device__ __forceinline__ float dppR(float v) {   // value from lane+1
    return __int_as_float(__builtin_amdgcn_update_dpp(
        0, __float_as_int(v), 0x130, 0xF, 0xF, false));
}
__device__ __forceinline__ unsigned pk2(float a, float b) {
    unsigned lo = __half_as_ushort(__float2half_rn(a));
    unsigned hi = __half_as_ushort(__float2half_rn(b));
    return lo | (hi << 16);
}
__device__ __forceinline__ float hlo(unsigned u) {
    const __half2 h = __builtin_bit_cast(__half2, u);
    return __half2float(h.x);
}
__device__ __forceinline__ float hhi(unsigned u) {
    const __half2 h = __builtin_bit_cast(__half2, u);
    return __half2float(h.y);
}

// window of one LDS row for this lane's 2 px: {c-1, c, c+1, c+2}
__device__ __forceinline__ float4 ldrow(const float* rowp, int lane) {
    const float2 v = *(const float2*)(rowp + 2 * lane);
    float4 w;
    w.x = dppL(v.y);      // col c-1 = left pair's .y
    w.y = v.x;
    w.z = v.y;
    w.w = dppR(v.x);      // col c+2 = right pair's .x
    return w;
}

// Single launch: inline softmax+mask fold into 40 weight VGPRs, then 16
// Jacobi steps in double-buffered LDS. Block-wide barriers replaced by
// per-strip LDS flag handshakes (wave s waits only on strips s+-1).
// Flags live in xs[1][0][0..15]: buf1 row 0 is written only by strip 0,
// which skips that write; row-0 values are trapezoid-don't-care, and any
// garbage/NaN read from it propagates 1 row/step, exactly one row behind
// the shrinking valid region -> never reaches the output tile.
__global__ __launch_bounds__(NT, 8) void prop16_kernel(
    const float* __restrict__ guided,   // (B,9,H,W)
    const float* __restrict__ x,        // (B,1,H,W)
    const float* __restrict__ sparse,   // (B,1,H,W)
    float* __restrict__ xout)           // (B,1,H,W)
{
    __shared__ float xs[2][PRY][PRX];   // 65,536 B exactly; 2 blocks/CU

    int* const flags = (int*)&xs[1][0][0];   // 16 step-counters

    const int tid  = threadIdx.x;
    const int lane = tid & 63;          // col pair (0..63)
    const int strip = tid >> 6;         // wave id = strip (0..15)
    const int r0 = strip * RPT;
    const int b = blockIdx.z;
    const int bx0 = blockIdx.x * PTX, by0 = blockIdx.y * PTY;
    const int gx0 = bx0 - PS, gy0 = by0 - PS;
    const size_t ob = (size_t)b * HW;

    // zero flags (first wave; ordered by the single barrier below)
    if (tid < NSTRIP) ((volatile int*)flags)[tid] = 0;

    // ---- fill OWN strip rows of buf0 (no cross-wave dependency) ----
    {
        const int gx = gx0 + 2 * lane;
        const bool cok = (gx >= 0) && (gx < W);
#pragma unroll
        for (int i = 0; i < RPT; ++i) {
            const int r = r0 + i;
            const int gy = gy0 + r;
            float2 v = make_float2(0.f, 0.f);
            if (cok && gy >= 0 && gy < H)
                v = *(const float2*)(x + ob + (size_t)gy * W + gx);
            *(float2*)&xs[0][r][2 * lane] = v;
        }
    }

    // ---- inline softmax + mask fold for own 2x4 px -> 40 weight u32 ----
    unsigned qe0[RPT], qe1[RPT], qe2[RPT], qe3[RPT], qe4[RPT];
    unsigned qo0[RPT], qo1[RPT], qo2[RPT], qo3[RPT], qo4[RPT];
    {
        const int gx = gx0 + 2 * lane;
        const bool cok = (gx >= 0) && (gx < W);
#pragma unroll
        for (int i = 0; i < RPT; ++i) {
            const int r = r0 + i;
            const int gy = gy0 + r;
            if (cok && gy >= 0 && gy < H) {
                const size_t p = (size_t)gy * W + gx;
                float2 g[9];
                float mex = -INFINITY, mey = -INFINITY;
#pragma unroll
                for (int k = 0; k < 9; ++k) {
                    g[k] = *(const float2*)(guided + ((size_t)(b * 9 + k)) * HW + p);
                    mex = fmaxf(mex, g[k].x);
                    mey = fmaxf(mey, g[k].y);
                }
                float se = 0.f, so = 0.f;
#pragma unroll
                for (int k = 0; k < 9; ++k) {
                    g[k].x = __expf(g[k].x - mex); se += g[k].x;
                    g[k].y = __expf(g[k].y - mey); so += g[k].y;
                }
                const float2 sv = *(const float2*)(sparse + ob + p);
                const float maske = (sv.x > 0.f) ? 1.f : 0.f;
                const float masko = (sv.y > 0.f) ? 1.f : 0.f;
                const float sce = (1.f - maske) / se;
                const float sco = (1.f - masko) / so;
                qe0[i] = pk2(g[0].x * sce, g[1].x * sce);
                qe1[i] = pk2(g[2].x * sce, g[3].x * sce);
                qe2[i] = pk2(g[4].x * sce, g[5].x * sce);
                qe3[i] = pk2(g[6].x * sce, g[7].x * sce);
                qe4[i] = pk2(g[8].x * sce, maske * xs[0][r][2 * lane]);
                qo0[i] = pk2(g[0].y * sco, g[1].y * sco);
                qo1[i] = pk2(g[2].y * sco, g[3].y * sco);
                qo2[i] = pk2(g[4].y * sco, g[5].y * sco);
                qo3[i] = pk2(g[6].y * sco, g[7].y * sco);
                qo4[i] = pk2(g[8].y * sco, masko * xs[0][r][2 * lane + 1]);
            } else {
                qe0[i] = qe1[i] = qe2[i] = qe3[i] = qe4[i] = 0u;
                qo0[i] = qo1[i] = qo2[i] = qo3[i] = qo4[i] = 0u;
            }
        }
    }
    __syncthreads();   // the ONLY pre-loop barrier: flags zeroed, fills visible

    const int rm1 = (strip == 0) ? 0 : (r0 - 1);          // clamped rim rows
    const int rb3 = (strip == NSTRIP - 1) ? (PRY - 1) : (r0 + RPT);

    // ---- 16 Jacobi steps; per-strip flag sync instead of barriers ----
    for (int t = 0; t < PS; ++t) {
        if (t > 0) {
            volatile int* vf = (volatile int*)flags;
            if (strip > 0) {
                int guard = 0;
                while (vf[strip - 1] < t && ++guard < (1 << 24))
                    __builtin_amdgcn_s_sleep(1);
            }
            if (strip < NSTRIP - 1) {
                int guard = 0;
                while (vf[strip + 1] < t && ++guard < (1 << 24))
                    __builtin_amdgcn_s_sleep(1);
            }
            asm volatile("" ::: "memory");   // reads stay after the poll
        }
        const float (*rd)[PRX] = xs[t & 1];
        float (*wr)[PRX] = xs[(t + 1) & 1];

        float4 T = ldrow(&rd[rm1][0], lane);
        float4 M = ldrow(&rd[r0][0], lane);
#pragma unroll
        for (int i = 0; i < RPT; ++i) {
            const int rb = (i == RPT - 1) ? rb3 : (r0 + i + 1);
            const float4 Bw = ldrow(&rd[rb][0], lane);
            // even px (col 2*lane): window cols {x,y,z} of each row
            float ae = hhi(qe4[i]);
            ae = fmaf(hlo(qe0[i]), T.x, ae);
            ae = fmaf(hhi(qe0[i]), T.y, ae);
            ae = fmaf(hlo(qe1[i]), T.z, ae);
            ae = fmaf(hhi(qe1[i]), M.x, ae);
            ae = fmaf(hlo(qe2[i]), M.y, ae);
            ae = fmaf(hhi(qe2[i]), M.z, ae);
            ae = fmaf(hlo(qe3[i]), Bw.x, ae);
            ae = fmaf(hhi(qe3[i]), Bw.y, ae);
            ae = fmaf(hlo(qe4[i]), Bw.z, ae);
            // odd px (col 2*lane+1): window cols {y,z,w}
            float ao = hhi(qo4[i]);
            ao = fmaf(hlo(qo0[i]), T.y, ao);
            ao = fmaf(hhi(qo0[i]), T.z, ao);
            ao = fmaf(hlo(qo1[i]), T.w, ao);
            ao = fmaf(hhi(qo1[i]), M.y, ao);
            ao = fmaf(hlo(qo2[i]), M.z, ao);
            ao = fmaf(hhi(qo2[i]), M.w, ao);
            ao = fmaf(hlo(qo3[i]), Bw.y, ao);
            ao = fmaf(hhi(qo3[i]), Bw.z, ao);
            ao = fmaf(hlo(qo4[i]), Bw.w, ao);
            if (i != 0 || strip != 0)       // strip 0 never writes row 0
                *(float2*)&wr[r0 + i][2 * lane] = make_float2(ae, ao);
            T = M; M = Bw;
        }
        // all our ds reads AND writes of this step must be complete before
        // publishing: neighbors may then overwrite our read-rows / read ours.
        asm volatile("s_waitcnt lgkmcnt(0)" ::: "memory");
        if (lane == 0) ((volatile int*)flags)[strip] = t + 1;
    }
    __syncthreads();   // all strips' step-15 writes visible for the writeout

    // ---- final values in buf0; write tile (coalesced) ----
    for (int i = tid; i < PTX * PTY; i += NT) {
        const int r = i / PTX, cc = i - r * PTX;
        const int gx = bx0 + cc;
        if (gx < W)
            xout[ob + (size_t)(by0 + r) * W + gx] = xs[0][PS + r][PS + cc];
    }
}

extern "C" void kernel_launch(void* const* d_in, const int* in_sizes, int n_in,
                              void* d_out, int out_size, void* d_ws, size_t ws_size,
                              hipStream_t stream) {
    const float* guided = (const float*)d_in[0];
    const float* x      = (const float*)d_in[1];
    const float* sparse = (const float*)d_in[2];
    float* out = (float*)d_out;

    dim3 blk(NT, 1, 1);
    dim3 grd((W + PTX - 1) / PTX, H / PTY, BATCH);   // 7 x 15 x 8 = 840 blocks
    prop16_kernel<<<grd, blk, 0, stream>>>(guided, x, sparse, out);
}

// Round 11
// 95.318 us; speedup vs baseline: 4.9943x; 4.9943x over previous
//
#include <hip/hip_runtime.h>
#include <hip/hip_fp16.h>
#include <math.h>

#define BATCH 8
#define H 480
#define W 640
#define HW (H * W)

// ---- single-launch geometry: all 16 steps fused ----
#define PS 16                 // fused steps (= total)
#define PTX 96                // output tile width
#define PTY 32                // output tile height
#define PRX 128               // region cols = PTX + 2*PS (= 64 lanes x 2)
#define PRY 64                // region rows = PTY + 2*PS
#define NT 1024               // 16 waves; wave = strip of 4 rows, lane = col-pair
#define RPT 4                 // rows per thread (held in registers)
#define NSTRIP 16

// DPP wave-wide shifts: lane i <- lane i-1 (0x138), lane i+1 (0x130).
// Shifted-in lanes take old (=0): region col -1 / col 128 read as 0 -> rim
// pixels only (trapezoid-stale-safe) or out-of-image pixels (w=0).
__device__ __forceinline__ float dppL(float v) {   // value from lane-1
    return __int_as_float(__builtin_amdgcn_update_dpp(
        0, __float_as_int(v), 0x138, 0xF, 0xF, false));
}
__device__ __forceinline__ float dppR(float v) {   // value from lane+1
    return __int_as_float(__builtin_amdgcn_update_dpp(
        0, __float_as_int(v), 0x130, 0xF, 0xF, false));
}
__device__ __forceinline__ unsigned pk2(float a, float b) {
    unsigned lo = __half_as_ushort(__float2half_rn(a));
    unsigned hi = __half_as_ushort(__float2half_rn(b));
    return lo | (hi << 16);
}
__device__ __forceinline__ float hlo(unsigned u) {
    const __half2 h = __builtin_bit_cast(__half2, u);
    return __half2float(h.x);
}
__device__ __forceinline__ float hhi(unsigned u) {
    const __half2 h = __builtin_bit_cast(__half2, u);
    return __half2float(h.y);
}

// 3x4 window of one row for this lane's 2 px: cols {c-1, c, c+1, c+2}
__device__ __forceinline__ float4 winp(float2 v) {
    float4 w;
    w.x = dppL(v.y);      // col c-1 = left pair's .y
    w.y = v.x;
    w.z = v.y;
    w.w = dppR(v.x);      // col c+2 = right pair's .x
    return w;
}

// one row-pair update: even px uses cols {x,y,z}, odd px uses {y,z,w}
__device__ __forceinline__ float2 pxp(
    unsigned e0, unsigned e1, unsigned e2, unsigned e3, unsigned e4,
    unsigned o0, unsigned o1, unsigned o2, unsigned o3, unsigned o4,
    float4 T, float4 M, float4 B)
{
    float ae = hhi(e4);                    // bias
    ae = fmaf(hlo(e0), T.x, ae);
    ae = fmaf(hhi(e0), T.y, ae);
    ae = fmaf(hlo(e1), T.z, ae);
    ae = fmaf(hhi(e1), M.x, ae);
    ae = fmaf(hlo(e2), M.y, ae);
    ae = fmaf(hhi(e2), M.z, ae);
    ae = fmaf(hlo(e3), B.x, ae);
    ae = fmaf(hhi(e3), B.y, ae);
    ae = fmaf(hlo(e4), B.z, ae);
    float ao = hhi(o4);
    ao = fmaf(hlo(o0), T.y, ao);
    ao = fmaf(hhi(o0), T.z, ao);
    ao = fmaf(hlo(o1), T.w, ao);
    ao = fmaf(hhi(o1), M.y, ao);
    ao = fmaf(hlo(o2), M.z, ao);
    ao = fmaf(hhi(o2), M.w, ao);
    ao = fmaf(hlo(o3), B.y, ao);
    ao = fmaf(hhi(o3), B.z, ao);
    ao = fmaf(hlo(o4), B.w, ao);
    return make_float2(ae, ao);
}

// Register-resident interior: each thread keeps its 4 rows (2 cols) of x in
// registers across all 16 steps. Only strip-boundary rows round-trip LDS
// (2 writes + 2 reads per step, double-buffered 32 KB). Windows (incl. +-1
// col) come from registers via DPP. One barrier per step. Clamped rim rows /
// stale rim cols are trapezoid-safe; out-of-image px have w=0,bias=0 -> 0.
__global__ __launch_bounds__(NT) void prop16_kernel(
    const float* __restrict__ guided,   // (B,9,H,W)
    const float* __restrict__ x,        // (B,1,H,W)
    const float* __restrict__ sparse,   // (B,1,H,W)
    float* __restrict__ xout)           // (B,1,H,W)
{
    __shared__ float bnd[2][NSTRIP][2][PRX];   // 32,768 B

    const int tid  = threadIdx.x;
    const int lane = tid & 63;          // col pair (0..63)
    const int strip = tid >> 6;         // wave id = strip (0..15)
    const int r0 = strip * RPT;
    const int b = blockIdx.z;
    const int bx0 = blockIdx.x * PTX, by0 = blockIdx.y * PTY;
    const int gx0 = bx0 - PS, gy0 = by0 - PS;
    const size_t ob = (size_t)b * HW;
    const int gx = gx0 + 2 * lane;
    const bool cok = (gx >= 0) && (gx < W);

    // ---- load own 4 rows of x into registers (zeros outside image) ----
    float2 x0_ = make_float2(0.f, 0.f), x1_ = x0_, x2_ = x0_, x3_ = x0_;
    {
        const int gy = gy0 + r0;
        if (cok) {
            if (gy >= 0 && gy < H)         x0_ = *(const float2*)(x + ob + (size_t)gy * W + gx);
            if (gy + 1 >= 0 && gy + 1 < H) x1_ = *(const float2*)(x + ob + (size_t)(gy + 1) * W + gx);
            if (gy + 2 >= 0 && gy + 2 < H) x2_ = *(const float2*)(x + ob + (size_t)(gy + 2) * W + gx);
            if (gy + 3 >= 0 && gy + 3 < H) x3_ = *(const float2*)(x + ob + (size_t)(gy + 3) * W + gx);
        }
    }
    // publish initial boundary rows (state 0 lives in bnd[0])
    *(float2*)&bnd[0][strip][0][2 * lane] = x0_;
    *(float2*)&bnd[0][strip][1][2 * lane] = x3_;

    // ---- inline softmax + mask fold for own 2x4 px -> 40 weight u32 ----
    unsigned qe0[RPT], qe1[RPT], qe2[RPT], qe3[RPT], qe4[RPT];
    unsigned qo0[RPT], qo1[RPT], qo2[RPT], qo3[RPT], qo4[RPT];
#define SMROW(i, xv) do {                                                   \
        const int gy = gy0 + r0 + (i);                                      \
        if (cok && gy >= 0 && gy < H) {                                     \
            const size_t p = (size_t)gy * W + gx;                           \
            float2 g[9];                                                    \
            float mex = -INFINITY, mey = -INFINITY;                         \
            _Pragma("unroll")                                               \
            for (int k = 0; k < 9; ++k) {                                   \
                g[k] = *(const float2*)(guided + ((size_t)(b * 9 + k)) * HW + p); \
                mex = fmaxf(mex, g[k].x);                                   \
                mey = fmaxf(mey, g[k].y);                                   \
            }                                                               \
            float se = 0.f, so = 0.f;                                       \
            _Pragma("unroll")                                               \
            for (int k = 0; k < 9; ++k) {                                   \
                g[k].x = __expf(g[k].x - mex); se += g[k].x;                \
                g[k].y = __expf(g[k].y - mey); so += g[k].y;                \
            }                                                               \
            const float2 sv = *(const float2*)(sparse + ob + p);            \
            const float maske = (sv.x > 0.f) ? 1.f : 0.f;                   \
            const float masko = (sv.y > 0.f) ? 1.f : 0.f;                   \
            const float sce = (1.f - maske) / se;                           \
            const float sco = (1.f - masko) / so;                           \
            qe0[i] = pk2(g[0].x * sce, g[1].x * sce);                       \
            qe1[i] = pk2(g[2].x * sce, g[3].x * sce);                       \
            qe2[i] = pk2(g[4].x * sce, g[5].x * sce);                       \
            qe3[i] = pk2(g[6].x * sce, g[7].x * sce);                       \
            qe4[i] = pk2(g[8].x * sce, maske * (xv).x);                     \
            qo0[i] = pk2(g[0].y * sco, g[1].y * sco);                       \
            qo1[i] = pk2(g[2].y * sco, g[3].y * sco);                       \
            qo2[i] = pk2(g[4].y * sco, g[5].y * sco);                       \
            qo3[i] = pk2(g[6].y * sco, g[7].y * sco);                       \
            qo4[i] = pk2(g[8].y * sco, masko * (xv).y);                     \
        } else {                                                            \
            qe0[i] = qe1[i] = qe2[i] = qe3[i] = qe4[i] = 0u;                \
            qo0[i] = qo1[i] = qo2[i] = qo3[i] = qo4[i] = 0u;                \
        }                                                                   \
    } while (0)
    SMROW(0, x0_);
    SMROW(1, x1_);
    SMROW(2, x2_);
    SMROW(3, x3_);
#undef SMROW
    __syncthreads();     // bnd[0] visible to neighbor strips

    // ---- 16 Jacobi steps; interior in registers, boundaries via LDS ----
    for (int t = 0; t < PS; ++t) {
        const int cur = t & 1, nxt = cur ^ 1;
        // boundary rows from neighbor strips (clamped at region rim)
        float2 tp, bp;
        if (strip > 0) tp = *(const float2*)&bnd[cur][strip - 1][1][2 * lane];
        else           tp = x0_;
        if (strip < NSTRIP - 1) bp = *(const float2*)&bnd[cur][strip + 1][0][2 * lane];
        else                    bp = x3_;
        // windows from registers (DPP for +-1 col)
        const float4 W0 = winp(x0_), W1 = winp(x1_), W2 = winp(x2_), W3 = winp(x3_);
        // interior rows first (no LDS dependency -> hides tp/bp latency)
        const float2 n1 = pxp(qe0[1], qe1[1], qe2[1], qe3[1], qe4[1],
                              qo0[1], qo1[1], qo2[1], qo3[1], qo4[1], W0, W1, W2);
        const float2 n2 = pxp(qe0[2], qe1[2], qe2[2], qe3[2], qe4[2],
                              qo0[2], qo1[2], qo2[2], qo3[2], qo4[2], W1, W2, W3);
        const float4 Tw = winp(tp);
        const float2 n0 = pxp(qe0[0], qe1[0], qe2[0], qe3[0], qe4[0],
                              qo0[0], qo1[0], qo2[0], qo3[0], qo4[0], Tw, W0, W1);
        const float4 Bw = winp(bp);
        const float2 n3 = pxp(qe0[3], qe1[3], qe2[3], qe3[3], qe4[3],
                              qo0[3], qo1[3], qo2[3], qo3[3], qo4[3], W2, W3, Bw);
        // publish new boundary rows into the next-parity buffer
        *(float2*)&bnd[nxt][strip][0][2 * lane] = n0;
        *(float2*)&bnd[nxt][strip][1][2 * lane] = n3;
        x0_ = n0; x1_ = n1; x2_ = n2; x3_ = n3;
        __syncthreads();   // everyone done reading bnd[cur] / writing bnd[nxt]
    }

    // ---- write own tile pixels straight from registers ----
    // tile interior rows = region rows [16,48) -> strips 4..11 entirely;
    // tile interior cols = region cols [16,112) -> lanes 8..55.
    if (strip >= 4 && strip < 12 &&
        (2 * lane) >= PS && (2 * lane) < PS + PTX && gx < W) {
        float* base = xout + ob + (size_t)(gy0 + r0) * W + gx;
        *(float2*)(base)          = x0_;
        *(float2*)(base + W)      = x1_;
        *(float2*)(base + 2 * W)  = x2_;
        *(float2*)(base + 3 * W)  = x3_;
    }
}

extern "C" void kernel_launch(void* const* d_in, const int* in_sizes, int n_in,
                              void* d_out, int out_size, void* d_ws, size_t ws_size,
                              hipStream_t stream) {
    const float* guided = (const float*)d_in[0];
    const float* x      = (const float*)d_in[1];
    const float* sparse = (const float*)d_in[2];
    float* out = (float*)d_out;

    dim3 blk(NT, 1, 1);
    dim3 grd((W + PTX - 1) / PTX, H / PTY, BATCH);   // 7 x 15 x 8 = 840 blocks
    prop16_kernel<<<grd, blk, 0, stream>>>(guided, x, sparse, out);
}

// Round 12
// 93.838 us; speedup vs baseline: 5.0731x; 1.0158x over previous
//
#include <hip/hip_runtime.h>
#include <hip/hip_fp16.h>
#include <math.h>

#define BATCH 8
#define H 480
#define W 640
#define HW (H * W)

// ---- single-launch geometry: all 16 steps fused ----
#define PS 16                 // fused steps (= total)
#define PTX 96                // output tile width
#define PTY 32                // output tile height
#define PRX 128               // region cols = PTX + 2*PS (= 64 lanes x 2)
#define PRY 64                // region rows = PTY + 2*PS
#define NT 1024               // 16 waves; wave = strip of 4 rows, lane = col-pair
#define RPT 4                 // rows per thread (held in registers)
#define NSTRIP 16

// DPP wave-wide shifts: lane i <- lane i-1 (0x138), lane i+1 (0x130).
// Shifted-in lanes take old (=0): region col -1 / col 128 read as 0 -> rim
// pixels only (trapezoid-stale-safe) or out-of-image pixels (w=0).
__device__ __forceinline__ float dppL(float v) {   // value from lane-1
    return __int_as_float(__builtin_amdgcn_update_dpp(
        0, __float_as_int(v), 0x138, 0xF, 0xF, false));
}
__device__ __forceinline__ float dppR(float v) {   // value from lane+1
    return __int_as_float(__builtin_amdgcn_update_dpp(
        0, __float_as_int(v), 0x130, 0xF, 0xF, false));
}

// 3x4 window of one row for this lane's 2 px: cols {c-1, c, c+1, c+2}
__device__ __forceinline__ float4 winp(float2 v) {
    float4 w;
    w.x = dppL(v.y);      // col c-1 = left pair's .y
    w.y = v.x;
    w.z = v.y;
    w.w = dppR(v.x);      // col c+2 = right pair's .x
    return w;
}

// row-pair update, all-f32 weights: even px taps {T.x,T.y,T.z / M... / B...},
// odd px taps {T.y,T.z,T.w / ... }. 18 v_fma_f32, no conversions.
#define PXR(i, Tw_, Mw_, Bw_) ({                                          \
    float ae_ = bs[i].x, ao_ = bs[i].y;                                    \
    ae_ = fmaf(wt[i][0].x, (Tw_).x, ae_); ao_ = fmaf(wt[i][0].y, (Tw_).y, ao_); \
    ae_ = fmaf(wt[i][1].x, (Tw_).y, ae_); ao_ = fmaf(wt[i][1].y, (Tw_).z, ao_); \
    ae_ = fmaf(wt[i][2].x, (Tw_).z, ae_); ao_ = fmaf(wt[i][2].y, (Tw_).w, ao_); \
    ae_ = fmaf(wt[i][3].x, (Mw_).x, ae_); ao_ = fmaf(wt[i][3].y, (Mw_).y, ao_); \
    ae_ = fmaf(wt[i][4].x, (Mw_).y, ae_); ao_ = fmaf(wt[i][4].y, (Mw_).z, ao_); \
    ae_ = fmaf(wt[i][5].x, (Mw_).z, ae_); ao_ = fmaf(wt[i][5].y, (Mw_).w, ao_); \
    ae_ = fmaf(wt[i][6].x, (Bw_).x, ae_); ao_ = fmaf(wt[i][6].y, (Bw_).y, ao_); \
    ae_ = fmaf(wt[i][7].x, (Bw_).y, ae_); ao_ = fmaf(wt[i][7].y, (Bw_).z, ao_); \
    ae_ = fmaf(wt[i][8].x, (Bw_).z, ae_); ao_ = fmaf(wt[i][8].y, (Bw_).w, ao_); \
    make_float2(ae_, ao_); })

// Register-resident interior (round-11 structure) with f32 register weights:
// each thread keeps its 4 rows (2 cols) of x AND its 2x4 px weights (9 taps +
// bias, float2 even/odd) in registers across all 16 steps. Only strip-boundary
// rows round-trip LDS (2 writes + 2 reads per step, double-buffered 32 KB).
// Windows (incl. +-1 col) via DPP. One barrier per step. Clamped rim rows /
// stale rim cols are trapezoid-safe; out-of-image px have w=0,bias=0 -> 0.
__global__ __launch_bounds__(NT) void prop16_kernel(
    const float* __restrict__ guided,   // (B,9,H,W)
    const float* __restrict__ x,        // (B,1,H,W)
    const float* __restrict__ sparse,   // (B,1,H,W)
    float* __restrict__ xout)           // (B,1,H,W)
{
    __shared__ float bnd[2][NSTRIP][2][PRX];   // 32,768 B

    const int tid  = threadIdx.x;
    const int lane = tid & 63;          // col pair (0..63)
    const int strip = tid >> 6;         // wave id = strip (0..15)
    const int r0 = strip * RPT;
    const int b = blockIdx.z;
    const int bx0 = blockIdx.x * PTX, by0 = blockIdx.y * PTY;
    const int gx0 = bx0 - PS, gy0 = by0 - PS;
    const size_t ob = (size_t)b * HW;
    const int gx = gx0 + 2 * lane;
    const bool cok = (gx >= 0) && (gx < W);

    // ---- load own 4 rows of x into registers (zeros outside image) ----
    float2 x0_ = make_float2(0.f, 0.f), x1_ = x0_, x2_ = x0_, x3_ = x0_;
    {
        const int gy = gy0 + r0;
        if (cok) {
            if (gy >= 0 && gy < H)         x0_ = *(const float2*)(x + ob + (size_t)gy * W + gx);
            if (gy + 1 >= 0 && gy + 1 < H) x1_ = *(const float2*)(x + ob + (size_t)(gy + 1) * W + gx);
            if (gy + 2 >= 0 && gy + 2 < H) x2_ = *(const float2*)(x + ob + (size_t)(gy + 2) * W + gx);
            if (gy + 3 >= 0 && gy + 3 < H) x3_ = *(const float2*)(x + ob + (size_t)(gy + 3) * W + gx);
        }
    }
    // publish initial boundary rows (state 0 lives in bnd[0])
    *(float2*)&bnd[0][strip][0][2 * lane] = x0_;
    *(float2*)&bnd[0][strip][1][2 * lane] = x3_;

    // ---- inline softmax + mask fold: f32 float2 (even,odd) weights ----
    float2 wt[RPT][9];      // wt[i][k] = tap-k weight for (even,odd) px
    float2 bs[RPT];         // bias (mask*x0) for (even,odd)
#define SMROW(i, xv) do {                                                   \
        const int gy = gy0 + r0 + (i);                                      \
        if (cok && gy >= 0 && gy < H) {                                     \
            const size_t p = (size_t)gy * W + gx;                           \
            float2 g[9];                                                    \
            float mex = -INFINITY, mey = -INFINITY;                         \
            _Pragma("unroll")                                               \
            for (int k = 0; k < 9; ++k) {                                   \
                g[k] = *(const float2*)(guided + ((size_t)(b * 9 + k)) * HW + p); \
                mex = fmaxf(mex, g[k].x);                                   \
                mey = fmaxf(mey, g[k].y);                                   \
            }                                                               \
            float se = 0.f, so = 0.f;                                       \
            _Pragma("unroll")                                               \
            for (int k = 0; k < 9; ++k) {                                   \
                g[k].x = __expf(g[k].x - mex); se += g[k].x;                \
                g[k].y = __expf(g[k].y - mey); so += g[k].y;                \
            }                                                               \
            const float2 sv = *(const float2*)(sparse + ob + p);            \
            const float maske = (sv.x > 0.f) ? 1.f : 0.f;                   \
            const float masko = (sv.y > 0.f) ? 1.f : 0.f;                   \
            const float sce = (1.f - maske) / se;                           \
            const float sco = (1.f - masko) / so;                           \
            _Pragma("unroll")                                               \
            for (int k = 0; k < 9; ++k)                                     \
                wt[i][k] = make_float2(g[k].x * sce, g[k].y * sco);         \
            bs[i] = make_float2(maske * (xv).x, masko * (xv).y);            \
        } else {                                                            \
            _Pragma("unroll")                                               \
            for (int k = 0; k < 9; ++k) wt[i][k] = make_float2(0.f, 0.f);   \
            bs[i] = make_float2(0.f, 0.f);                                  \
        }                                                                   \
    } while (0)
    SMROW(0, x0_);
    SMROW(1, x1_);
    SMROW(2, x2_);
    SMROW(3, x3_);
#undef SMROW
    __syncthreads();     // bnd[0] visible to neighbor strips

    // ---- 16 Jacobi steps; interior in registers, boundaries via LDS ----
    for (int t = 0; t < PS; ++t) {
        const int cur = t & 1, nxt = cur ^ 1;
        // boundary rows from neighbor strips (clamped at region rim)
        float2 tp, bp;
        if (strip > 0) tp = *(const float2*)&bnd[cur][strip - 1][1][2 * lane];
        else           tp = x0_;
        if (strip < NSTRIP - 1) bp = *(const float2*)&bnd[cur][strip + 1][0][2 * lane];
        else                    bp = x3_;
        // windows from registers (DPP for +-1 col)
        const float4 W0 = winp(x0_), W1 = winp(x1_), W2 = winp(x2_), W3 = winp(x3_);
        // interior rows first (no LDS dependency -> hides tp/bp latency)
        const float2 n1 = PXR(1, W0, W1, W2);
        const float2 n2 = PXR(2, W1, W2, W3);
        const float4 Tw = winp(tp);
        const float2 n0 = PXR(0, Tw, W0, W1);
        const float4 Bw = winp(bp);
        const float2 n3 = PXR(3, W2, W3, Bw);
        // publish new boundary rows into the next-parity buffer
        *(float2*)&bnd[nxt][strip][0][2 * lane] = n0;
        *(float2*)&bnd[nxt][strip][1][2 * lane] = n3;
        x0_ = n0; x1_ = n1; x2_ = n2; x3_ = n3;
        __syncthreads();   // everyone done reading bnd[cur] / writing bnd[nxt]
    }

    // ---- write own tile pixels straight from registers ----
    // tile interior rows = region rows [16,48) -> strips 4..11 entirely;
    // tile interior cols = region cols [16,112) -> lanes 8..55.
    if (strip >= 4 && strip < 12 &&
        (2 * lane) >= PS && (2 * lane) < PS + PTX && gx < W) {
        float* base = xout + ob + (size_t)(gy0 + r0) * W + gx;
        *(float2*)(base)          = x0_;
        *(float2*)(base + W)      = x1_;
        *(float2*)(base + 2 * W)  = x2_;
        *(float2*)(base + 3 * W)  = x3_;
    }
}

extern "C" void kernel_launch(void* const* d_in, const int* in_sizes, int n_in,
                              void* d_out, int out_size, void* d_ws, size_t ws_size,
                              hipStream_t stream) {
    const float* guided = (const float*)d_in[0];
    const float* x      = (const float*)d_in[1];
    const float* sparse = (const float*)d_in[2];
    float* out = (float*)d_out;

    dim3 blk(NT, 1, 1);
    dim3 grd((W + PTX - 1) / PTX, H / PTY, BATCH);   // 7 x 15 x 8 = 840 blocks
    prop16_kernel<<<grd, blk, 0, stream>>>(guided, x, sparse, out);
}

// Round 13
// 87.299 us; speedup vs baseline: 5.4531x; 1.0749x over previous
//
#include <hip/hip_runtime.h>
#include <hip/hip_fp16.h>
#include <math.h>

#define BATCH 8
#define H 480
#define W 640
#define HW (H * W)

// ---- single-launch geometry: all 16 steps fused ----
#define PS 16                 // fused steps (= total)
#define PTX 96                // output tile width
#define PTY 32                // output tile height
#define PRX 128               // region cols = PTX + 2*PS (= 64 lanes x 2)
#define PRY 64                // region rows = PTY + 2*PS
#define NT 1024               // 16 waves; wave = strip of 4 rows, lane = col-pair
#define RPT 4                 // rows per thread (held in registers)
#define NSTRIP 16

typedef __half2 h2;

__device__ __forceinline__ unsigned h2u(h2 v) { return __builtin_bit_cast(unsigned, v); }
__device__ __forceinline__ h2 u2h(unsigned u) { return __builtin_bit_cast(h2, u); }

// DPP wave-wide shifts: lane i <- lane i-1 (0x138) / lane i+1 (0x130);
// shifted-in lanes get 0 (region rim: trapezoid-stale-safe / w=0 px).
__device__ __forceinline__ h2 dppLh(h2 v) {
    return u2h((unsigned)__builtin_amdgcn_update_dpp(
        0, (int)h2u(v), 0x138, 0xF, 0xF, false));
}
__device__ __forceinline__ h2 dppRh(h2 v) {
    return u2h((unsigned)__builtin_amdgcn_update_dpp(
        0, (int)h2u(v), 0x130, 0xF, 0xF, false));
}
// {lo = b.hi, hi = a.lo}  (v_alignbit_b32 a, b, 16)
__device__ __forceinline__ h2 algn(h2 a, h2 b) {
    return u2h(__builtin_amdgcn_alignbit(h2u(a), h2u(b), 16));
}

// Window of one row for this lane's (even,odd) px pair:
//  C = (e,o) itself; L = (e-1,o-1) = {prev.hi, C.lo}; R = (e+1,o+1) = {C.hi, next.lo}
struct Win { h2 L, C, R; };
__device__ __forceinline__ Win mkwin(h2 c) {
    Win w;
    w.C = c;
    w.L = algn(c, dppLh(c));
    w.R = algn(dppRh(c), c);
    return w;
}

// 9-tap packed update for one output row: 9 x v_pk_fma_f16, no conversions.
__device__ __forceinline__ h2 rowpx(const h2* wt, h2 bias, Win T, Win M, Win B) {
    h2 a = bias;
    a = __hfma2(wt[0], T.L, a);
    a = __hfma2(wt[1], T.C, a);
    a = __hfma2(wt[2], T.R, a);
    a = __hfma2(wt[3], M.L, a);
    a = __hfma2(wt[4], M.C, a);
    a = __hfma2(wt[5], M.R, a);
    a = __hfma2(wt[6], B.L, a);
    a = __hfma2(wt[7], B.C, a);
    a = __hfma2(wt[8], B.R, a);
    return a;
}

// Register-resident interior, packed-fp16 math: each thread keeps its 4 rows
// (2 cols, one __half2 each) of x and its 4x9 tap weights + bias (all __half2)
// in registers across all 16 steps. Only strip-boundary rows round-trip LDS
// (2 u32 writes + 2 u32 reads per step, double-buffered 16 KB). One barrier
// per step. Rim rows/cols clamped/zero: trapezoid-safe; out-of-image px have
// w=0,bias=0 -> stay exactly 0 (zero-pad semantics).
__global__ __launch_bounds__(NT) void prop16_kernel(
    const float* __restrict__ guided,   // (B,9,H,W)
    const float* __restrict__ x,        // (B,1,H,W)
    const float* __restrict__ sparse,   // (B,1,H,W)
    float* __restrict__ xout)           // (B,1,H,W)
{
    __shared__ unsigned bnd[2][NSTRIP][2][64];   // 16,384 B

    const int tid  = threadIdx.x;
    const int lane = tid & 63;          // col pair (0..63)
    const int strip = tid >> 6;         // wave id = strip (0..15)
    const int r0 = strip * RPT;
    const int b = blockIdx.z;
    const int bx0 = blockIdx.x * PTX, by0 = blockIdx.y * PTY;
    const int gx0 = bx0 - PS, gy0 = by0 - PS;
    const size_t ob = (size_t)b * HW;
    const int gx = gx0 + 2 * lane;
    const bool cok = (gx >= 0) && (gx < W);

    // ---- load own 4 rows of x (f32 pairs -> fp16 pairs; zeros outside) ----
    h2 x0_ = __floats2half2_rn(0.f, 0.f), x1_ = x0_, x2_ = x0_, x3_ = x0_;
    float2 xf[RPT];
#pragma unroll
    for (int i = 0; i < RPT; ++i) xf[i] = make_float2(0.f, 0.f);
    {
        const int gy = gy0 + r0;
        if (cok) {
            if (gy >= 0 && gy < H)         xf[0] = *(const float2*)(x + ob + (size_t)gy * W + gx);
            if (gy + 1 >= 0 && gy + 1 < H) xf[1] = *(const float2*)(x + ob + (size_t)(gy + 1) * W + gx);
            if (gy + 2 >= 0 && gy + 2 < H) xf[2] = *(const float2*)(x + ob + (size_t)(gy + 2) * W + gx);
            if (gy + 3 >= 0 && gy + 3 < H) xf[3] = *(const float2*)(x + ob + (size_t)(gy + 3) * W + gx);
        }
        x0_ = __floats2half2_rn(xf[0].x, xf[0].y);
        x1_ = __floats2half2_rn(xf[1].x, xf[1].y);
        x2_ = __floats2half2_rn(xf[2].x, xf[2].y);
        x3_ = __floats2half2_rn(xf[3].x, xf[3].y);
    }
    // publish initial boundary rows (state 0 lives in bnd[0])
    bnd[0][strip][0][lane] = h2u(x0_);
    bnd[0][strip][1][lane] = h2u(x3_);

    // ---- inline softmax + mask fold -> packed fp16 weights in registers ----
    h2 wt[RPT][9];      // wt[i][k] = tap-k (even,odd) weight pair
    h2 bs[RPT];         // bias (mask*x0) pair
#define SMROW(i) do {                                                       \
        const int gy = gy0 + r0 + (i);                                      \
        if (cok && gy >= 0 && gy < H) {                                     \
            const size_t p = (size_t)gy * W + gx;                           \
            float2 g[9];                                                    \
            float mex = -INFINITY, mey = -INFINITY;                         \
            _Pragma("unroll")                                               \
            for (int k = 0; k < 9; ++k) {                                   \
                g[k] = *(const float2*)(guided + ((size_t)(b * 9 + k)) * HW + p); \
                mex = fmaxf(mex, g[k].x);                                   \
                mey = fmaxf(mey, g[k].y);                                   \
            }                                                               \
            float se = 0.f, so = 0.f;                                       \
            _Pragma("unroll")                                               \
            for (int k = 0; k < 9; ++k) {                                   \
                g[k].x = __expf(g[k].x - mex); se += g[k].x;                \
                g[k].y = __expf(g[k].y - mey); so += g[k].y;                \
            }                                                               \
            const float2 sv = *(const float2*)(sparse + ob + p);            \
            const float maske = (sv.x > 0.f) ? 1.f : 0.f;                   \
            const float masko = (sv.y > 0.f) ? 1.f : 0.f;                   \
            const float sce = (1.f - maske) / se;                           \
            const float sco = (1.f - masko) / so;                           \
            _Pragma("unroll")                                               \
            for (int k = 0; k < 9; ++k)                                     \
                wt[i][k] = __floats2half2_rn(g[k].x * sce, g[k].y * sco);   \
            bs[i] = __floats2half2_rn(maske * xf[i].x, masko * xf[i].y);    \
        } else {                                                            \
            _Pragma("unroll")                                               \
            for (int k = 0; k < 9; ++k) wt[i][k] = __floats2half2_rn(0.f, 0.f); \
            bs[i] = __floats2half2_rn(0.f, 0.f);                            \
        }                                                                   \
    } while (0)
    SMROW(0);
    SMROW(1);
    SMROW(2);
    SMROW(3);
#undef SMROW
    __syncthreads();     // bnd[0] visible to neighbor strips

    // ---- 16 Jacobi steps; interior in registers, boundaries via LDS ----
    for (int t = 0; t < PS; ++t) {
        const int cur = t & 1, nxt = cur ^ 1;
        // boundary rows from neighbor strips (clamped at region rim)
        h2 tp, bp;
        if (strip > 0) tp = u2h(bnd[cur][strip - 1][1][lane]);
        else           tp = x0_;
        if (strip < NSTRIP - 1) bp = u2h(bnd[cur][strip + 1][0][lane]);
        else                    bp = x3_;
        // windows from registers (DPP + alignbit for +-1 col)
        const Win W0 = mkwin(x0_), W1 = mkwin(x1_), W2 = mkwin(x2_), W3 = mkwin(x3_);
        // interior rows first (no LDS dependency -> hides tp/bp latency)
        const h2 n1 = rowpx(wt[1], bs[1], W0, W1, W2);
        const h2 n2 = rowpx(wt[2], bs[2], W1, W2, W3);
        const Win Tw = mkwin(tp);
        const h2 n0 = rowpx(wt[0], bs[0], Tw, W0, W1);
        const Win Bw = mkwin(bp);
        const h2 n3 = rowpx(wt[3], bs[3], W2, W3, Bw);
        // publish new boundary rows into the next-parity buffer
        bnd[nxt][strip][0][lane] = h2u(n0);
        bnd[nxt][strip][1][lane] = h2u(n3);
        x0_ = n0; x1_ = n1; x2_ = n2; x3_ = n3;
        __syncthreads();   // everyone done reading bnd[cur] / writing bnd[nxt]
    }

    // ---- write own tile pixels straight from registers (f32 out) ----
    // tile interior rows = region rows [16,48) -> strips 4..11 entirely;
    // tile interior cols = region cols [16,112) -> lanes 8..55.
    if (strip >= 4 && strip < 12 &&
        (2 * lane) >= PS && (2 * lane) < PS + PTX && gx < W) {
        float* base = xout + ob + (size_t)(gy0 + r0) * W + gx;
        const float2 o0 = __half22float2(x0_);
        const float2 o1 = __half22float2(x1_);
        const float2 o2 = __half22float2(x2_);
        const float2 o3 = __half22float2(x3_);
        *(float2*)(base)         = o0;
        *(float2*)(base + W)     = o1;
        *(float2*)(base + 2 * W) = o2;
        *(float2*)(base + 3 * W) = o3;
    }
}

extern "C" void kernel_launch(void* const* d_in, const int* in_sizes, int n_in,
                              void* d_out, int out_size, void* d_ws, size_t ws_size,
                              hipStream_t stream) {
    const float* guided = (const float*)d_in[0];
    const float* x      = (const float*)d_in[1];
    const float* sparse = (const float*)d_in[2];
    float* out = (float*)d_out;

    dim3 blk(NT, 1, 1);
    dim3 grd((W + PTX - 1) / PTX, H / PTY, BATCH);   // 7 x 15 x 8 = 840 blocks
    prop16_kernel<<<grd, blk, 0, stream>>>(guided, x, sparse, out);
}

// Round 14
// 79.738 us; speedup vs baseline: 5.9702x; 1.0948x over previous
//
#include <hip/hip_runtime.h>
#include <hip/hip_fp16.h>
#include <math.h>

#define BATCH 8
#define H 480
#define W 640
#define HW (H * W)

// ---- single-launch geometry: all 16 steps fused, big patch ----
#define PS 16                 // fused steps (= total)
#define PTX 96                // output tile width
#define PTY 96                // output tile height
#define PRX 128               // region cols = PTX + 2*PS (= 64 lanes x 2)
#define PRY 128               // region rows = PTY + 2*PS
#define NT 1024               // 16 waves; wave = strip, lane = col pair
#define RPT 8                 // rows per thread (held in registers)
#define NSTRIP 16

typedef __half2 h2;

__device__ __forceinline__ unsigned h2u(h2 v) { return __builtin_bit_cast(unsigned, v); }
__device__ __forceinline__ h2 u2h(unsigned u) { return __builtin_bit_cast(h2, u); }

// DPP wave-wide shifts: lane i <- lane i-1 (0x138) / lane i+1 (0x130);
// shifted-in lanes get 0 (region rim: trapezoid-stale-safe / w=0 px).
__device__ __forceinline__ h2 dppLh(h2 v) {
    return u2h((unsigned)__builtin_amdgcn_update_dpp(
        0, (int)h2u(v), 0x138, 0xF, 0xF, false));
}
__device__ __forceinline__ h2 dppRh(h2 v) {
    return u2h((unsigned)__builtin_amdgcn_update_dpp(
        0, (int)h2u(v), 0x130, 0xF, 0xF, false));
}
// {lo = b.hi, hi = a.lo}  (v_alignbit_b32 a, b, 16)
__device__ __forceinline__ h2 algn(h2 a, h2 b) {
    return u2h(__builtin_amdgcn_alignbit(h2u(a), h2u(b), 16));
}

// Window of one row for this lane's (even,odd) px pair:
//  C = pair itself; L = (e-1,o-1) = {prev.hi, C.lo}; R = (e+1,o+1) = {C.hi, next.lo}
struct Win { h2 L, C, R; };
__device__ __forceinline__ Win mkwin(h2 c) {
    Win w;
    w.C = c;
    w.L = algn(c, dppLh(c));
    w.R = algn(dppRh(c), c);
    return w;
}

// 9-tap packed update for one output row: 9 x v_pk_fma_f16, no conversions.
__device__ __forceinline__ h2 rowpx(const h2* wt, h2 bias, Win T, Win M, Win B) {
    h2 a = bias;
    a = __hfma2(wt[0], T.L, a);
    a = __hfma2(wt[1], T.C, a);
    a = __hfma2(wt[2], T.R, a);
    a = __hfma2(wt[3], M.L, a);
    a = __hfma2(wt[4], M.C, a);
    a = __hfma2(wt[5], M.R, a);
    a = __hfma2(wt[6], B.L, a);
    a = __hfma2(wt[7], B.C, a);
    a = __hfma2(wt[8], B.R, a);
    return a;
}

// Register-resident interior, packed-fp16 math, 2x8 px per thread:
// x state (8 h2), tap weights (72 h2) and bias (8 h2) live in registers all
// 16 steps. Only strip-boundary rows round-trip LDS (double-buffered 16 KB).
// Rolling 3-row window keeps the live set small. One barrier per step.
// Rim rows/cols clamped/zero: trapezoid-safe; out-of-image px have
// w=0,bias=0 -> stay exactly 0 (zero-pad semantics).
__global__ __launch_bounds__(NT) void prop16_kernel(
    const float* __restrict__ guided,   // (B,9,H,W)
    const float* __restrict__ x,        // (B,1,H,W)
    const float* __restrict__ sparse,   // (B,1,H,W)
    float* __restrict__ xout)           // (B,1,H,W)
{
    __shared__ unsigned bnd[2][NSTRIP][2][64];   // 16,384 B

    const int tid  = threadIdx.x;
    const int lane = tid & 63;          // col pair (0..63)
    const int strip = tid >> 6;         // wave id = strip (0..15)
    const int r0 = strip * RPT;
    const int b = blockIdx.z;
    const int bx0 = blockIdx.x * PTX, by0 = blockIdx.y * PTY;
    const int gx0 = bx0 - PS, gy0 = by0 - PS;
    const size_t ob = (size_t)b * HW;
    const int gx = gx0 + 2 * lane;
    const bool cok = (gx >= 0) && (gx < W);

    // ---- per-row: load x, inline softmax + mask fold -> registers ----
    h2 xr[RPT];         // x state (even,odd col pair), fp16
    h2 wt[RPT][9];      // tap weights
    h2 bs[RPT];         // bias (mask * x0)
#pragma unroll
    for (int i = 0; i < RPT; ++i) {
        const int gy = gy0 + r0 + i;
        if (cok && gy >= 0 && gy < H) {
            const size_t p = (size_t)gy * W + gx;
            const float2 xf = *(const float2*)(x + ob + p);
            xr[i] = __floats2half2_rn(xf.x, xf.y);
            float2 g[9];
            float mex = -INFINITY, mey = -INFINITY;
#pragma unroll
            for (int k = 0; k < 9; ++k) {
                g[k] = *(const float2*)(guided + ((size_t)(b * 9 + k)) * HW + p);
                mex = fmaxf(mex, g[k].x);
                mey = fmaxf(mey, g[k].y);
            }
            float se = 0.f, so = 0.f;
#pragma unroll
            for (int k = 0; k < 9; ++k) {
                g[k].x = __expf(g[k].x - mex); se += g[k].x;
                g[k].y = __expf(g[k].y - mey); so += g[k].y;
            }
            const float2 sv = *(const float2*)(sparse + ob + p);
            const float maske = (sv.x > 0.f) ? 1.f : 0.f;
            const float masko = (sv.y > 0.f) ? 1.f : 0.f;
            const float sce = (1.f - maske) / se;
            const float sco = (1.f - masko) / so;
#pragma unroll
            for (int k = 0; k < 9; ++k)
                wt[i][k] = __floats2half2_rn(g[k].x * sce, g[k].y * sco);
            bs[i] = __floats2half2_rn(maske * xf.x, masko * xf.y);
        } else {
            xr[i] = __floats2half2_rn(0.f, 0.f);
#pragma unroll
            for (int k = 0; k < 9; ++k) wt[i][k] = __floats2half2_rn(0.f, 0.f);
            bs[i] = __floats2half2_rn(0.f, 0.f);
        }
    }
    // publish initial boundary rows (state 0 lives in bnd[0])
    bnd[0][strip][0][lane] = h2u(xr[0]);
    bnd[0][strip][1][lane] = h2u(xr[RPT - 1]);
    __syncthreads();     // bnd[0] visible to neighbor strips

    // ---- 16 Jacobi steps; interior in registers, boundaries via LDS ----
    for (int t = 0; t < PS; ++t) {
        const int cur = t & 1, nxt = cur ^ 1;
        // boundary rows from neighbor strips (clamped at region rim)
        h2 tp, bp;
        if (strip > 0) tp = u2h(bnd[cur][strip - 1][1][lane]);
        else           tp = xr[0];
        if (strip < NSTRIP - 1) bp = u2h(bnd[cur][strip + 1][0][lane]);
        else                    bp = xr[RPT - 1];
        // rolling 3-row window down the strip; T/M/B hold pre-update values
        Win T = mkwin(tp);
        Win M = mkwin(xr[0]);
        h2 nfirst;
#pragma unroll
        for (int r = 0; r < RPT; ++r) {
            const Win B = mkwin((r < RPT - 1) ? xr[r + 1] : bp);
            const h2 n = rowpx(wt[r], bs[r], T, M, B);
            if (r == 0) nfirst = n;
            xr[r] = n;
            T = M; M = B;
        }
        // publish new boundary rows into the next-parity buffer
        bnd[nxt][strip][0][lane] = h2u(nfirst);
        bnd[nxt][strip][1][lane] = h2u(xr[RPT - 1]);
        __syncthreads();   // everyone done reading bnd[cur] / writing bnd[nxt]
    }

    // ---- write own tile pixels straight from registers (f32 out) ----
    // tile interior rows = region rows [16,112) -> strips 2..13 entirely;
    // tile interior cols = region cols [16,112) -> lanes 8..55.
    if (strip >= 2 && strip < 14 &&
        (2 * lane) >= PS && (2 * lane) < PS + PTX && gx < W) {
        float* base = xout + ob + (size_t)(gy0 + r0) * W + gx;
#pragma unroll
        for (int i = 0; i < RPT; ++i) {
            const float2 o = __half22float2(xr[i]);
            *(float2*)(base + (size_t)i * W) = o;
        }
    }
}

extern "C" void kernel_launch(void* const* d_in, const int* in_sizes, int n_in,
                              void* d_out, int out_size, void* d_ws, size_t ws_size,
                              hipStream_t stream) {
    const float* guided = (const float*)d_in[0];
    const float* x      = (const float*)d_in[1];
    const float* sparse = (const float*)d_in[2];
    float* out = (float*)d_out;

    dim3 blk(NT, 1, 1);
    dim3 grd((W + PTX - 1) / PTX, H / PTY, BATCH);   // 7 x 5 x 8 = 280 blocks
    prop16_kernel<<<grd, blk, 0, stream>>>(guided, x, sparse, out);
}

// Round 15
// 66.075 us; speedup vs baseline: 7.2047x; 1.2068x over previous
//
#include <hip/hip_runtime.h>
#include <hip/hip_fp16.h>
#include <math.h>

#define BATCH 8
#define H 480
#define W 640
#define HW (H * W)

// ---- single-launch geometry: all 16 steps fused, grid fits in one batch ----
#define PS 16                 // fused steps (= total)
#define PTX 96                // output tile width
#define PTY 128               // output tile height
#define PRX 128               // region cols = PTX + 2*PS (= 64 lanes x 2)
#define PRY 160               // region rows = PTY + 2*PS = NSTRIP * RPT
#define NT 1024               // 16 waves; wave = strip, lane = col pair
#define RPT 10                // rows per thread (held in registers)
#define NSTRIP 16

typedef __half2 h2;

__device__ __forceinline__ unsigned h2u(h2 v) { return __builtin_bit_cast(unsigned, v); }
__device__ __forceinline__ h2 u2h(unsigned u) { return __builtin_bit_cast(h2, u); }

// DPP wave-wide shifts: lane i <- lane i-1 (0x138) / lane i+1 (0x130);
// shifted-in lanes get 0 (region rim: trapezoid-stale-safe / w=0 px).
__device__ __forceinline__ h2 dppLh(h2 v) {
    return u2h((unsigned)__builtin_amdgcn_update_dpp(
        0, (int)h2u(v), 0x138, 0xF, 0xF, false));
}
__device__ __forceinline__ h2 dppRh(h2 v) {
    return u2h((unsigned)__builtin_amdgcn_update_dpp(
        0, (int)h2u(v), 0x130, 0xF, 0xF, false));
}
// {lo = b.hi, hi = a.lo}  (v_alignbit_b32 a, b, 16)
__device__ __forceinline__ h2 algn(h2 a, h2 b) {
    return u2h(__builtin_amdgcn_alignbit(h2u(a), h2u(b), 16));
}

// Window of one row for this lane's (even,odd) px pair:
//  C = pair itself; L = {prev.hi, C.lo}; R = {C.hi, next.lo}
struct Win { h2 L, C, R; };
__device__ __forceinline__ Win mkwin(h2 c) {
    Win w;
    w.C = c;
    w.L = algn(c, dppLh(c));
    w.R = algn(dppRh(c), c);
    return w;
}

// 9-tap packed update for one output row: 9 x v_pk_fma_f16, no conversions.
__device__ __forceinline__ h2 rowpx(const h2* wt, h2 bias, Win T, Win M, Win B) {
    h2 a = bias;
    a = __hfma2(wt[0], T.L, a);
    a = __hfma2(wt[1], T.C, a);
    a = __hfma2(wt[2], T.R, a);
    a = __hfma2(wt[3], M.L, a);
    a = __hfma2(wt[4], M.C, a);
    a = __hfma2(wt[5], M.R, a);
    a = __hfma2(wt[6], B.L, a);
    a = __hfma2(wt[7], B.C, a);
    a = __hfma2(wt[8], B.R, a);
    return a;
}

// Register-resident interior, packed-fp16 math, 2x10 px per thread:
// x state (10 h2), tap weights (90 h2) and bias (10 h2) live in registers all
// 16 steps (unified VGPR/AGPR file). Only strip-boundary rows round-trip LDS
// (double-buffered 16 KB). Rolling 3-row window. One barrier per step.
// Rim rows/cols clamped/zero: trapezoid-safe; out-of-image px have
// w=0,bias=0 -> stay exactly 0 (zero-pad semantics).
__global__ __launch_bounds__(NT) void prop16_kernel(
    const float* __restrict__ guided,   // (B,9,H,W)
    const float* __restrict__ x,        // (B,1,H,W)
    const float* __restrict__ sparse,   // (B,1,H,W)
    float* __restrict__ xout)           // (B,1,H,W)
{
    __shared__ unsigned bnd[2][NSTRIP][2][64];   // 16,384 B

    const int tid  = threadIdx.x;
    const int lane = tid & 63;          // col pair (0..63)
    const int strip = tid >> 6;         // wave id = strip (0..15)
    const int r0 = strip * RPT;
    const int b = blockIdx.z;
    const int bx0 = blockIdx.x * PTX, by0 = blockIdx.y * PTY;
    const int gx0 = bx0 - PS, gy0 = by0 - PS;
    const size_t ob = (size_t)b * HW;
    const int gx = gx0 + 2 * lane;
    const bool cok = (gx >= 0) && (gx < W);

    // ---- per-row: load x, inline softmax + mask fold -> registers ----
    h2 xr[RPT];         // x state (even,odd col pair), fp16
    h2 wt[RPT][9];      // tap weights
    h2 bs[RPT];         // bias (mask * x0)
#pragma unroll
    for (int i = 0; i < RPT; ++i) {
        const int gy = gy0 + r0 + i;
        if (cok && gy >= 0 && gy < H) {
            const size_t p = (size_t)gy * W + gx;
            const float2 xf = *(const float2*)(x + ob + p);
            xr[i] = __floats2half2_rn(xf.x, xf.y);
            float2 g[9];
            float mex = -INFINITY, mey = -INFINITY;
#pragma unroll
            for (int k = 0; k < 9; ++k) {
                g[k] = *(const float2*)(guided + ((size_t)(b * 9 + k)) * HW + p);
                mex = fmaxf(mex, g[k].x);
                mey = fmaxf(mey, g[k].y);
            }
            float se = 0.f, so = 0.f;
#pragma unroll
            for (int k = 0; k < 9; ++k) {
                g[k].x = __expf(g[k].x - mex); se += g[k].x;
                g[k].y = __expf(g[k].y - mey); so += g[k].y;
            }
            const float2 sv = *(const float2*)(sparse + ob + p);
            const float maske = (sv.x > 0.f) ? 1.f : 0.f;
            const float masko = (sv.y > 0.f) ? 1.f : 0.f;
            const float sce = (1.f - maske) / se;
            const float sco = (1.f - masko) / so;
#pragma unroll
            for (int k = 0; k < 9; ++k)
                wt[i][k] = __floats2half2_rn(g[k].x * sce, g[k].y * sco);
            bs[i] = __floats2half2_rn(maske * xf.x, masko * xf.y);
        } else {
            xr[i] = __floats2half2_rn(0.f, 0.f);
#pragma unroll
            for (int k = 0; k < 9; ++k) wt[i][k] = __floats2half2_rn(0.f, 0.f);
            bs[i] = __floats2half2_rn(0.f, 0.f);
        }
    }
    // publish initial boundary rows (state 0 lives in bnd[0])
    bnd[0][strip][0][lane] = h2u(xr[0]);
    bnd[0][strip][1][lane] = h2u(xr[RPT - 1]);
    __syncthreads();     // bnd[0] visible to neighbor strips

    // ---- 16 Jacobi steps; interior in registers, boundaries via LDS ----
    for (int t = 0; t < PS; ++t) {
        const int cur = t & 1, nxt = cur ^ 1;
        // boundary rows from neighbor strips (clamped at region rim)
        h2 tp, bp;
        if (strip > 0) tp = u2h(bnd[cur][strip - 1][1][lane]);
        else           tp = xr[0];
        if (strip < NSTRIP - 1) bp = u2h(bnd[cur][strip + 1][0][lane]);
        else                    bp = xr[RPT - 1];
        // rolling 3-row window down the strip; T/M/B hold pre-update values
        Win T = mkwin(tp);
        Win M = mkwin(xr[0]);
        h2 nfirst;
#pragma unroll
        for (int r = 0; r < RPT; ++r) {
            const Win B = mkwin((r < RPT - 1) ? xr[r + 1] : bp);
            const h2 n = rowpx(wt[r], bs[r], T, M, B);
            if (r == 0) nfirst = n;
            xr[r] = n;
            T = M; M = B;
        }
        // publish new boundary rows into the next-parity buffer
        bnd[nxt][strip][0][lane] = h2u(nfirst);
        bnd[nxt][strip][1][lane] = h2u(xr[RPT - 1]);
        __syncthreads();   // everyone done reading bnd[cur] / writing bnd[nxt]
    }

    // ---- write own tile pixels straight from registers (f32 out) ----
    // tile interior cols = region cols [16,112) -> lanes 8..55;
    // tile interior rows = region rows [16,144), guarded per row.
    if ((2 * lane) >= PS && (2 * lane) < PS + PTX && gx < W) {
#pragma unroll
        for (int i = 0; i < RPT; ++i) {
            const int rr = r0 + i;
            const int gy = gy0 + rr;
            if (rr >= PS && rr < PS + PTY && gy < H) {
                const float2 o = __half22float2(xr[i]);
                *(float2*)(xout + ob + (size_t)gy * W + gx) = o;
            }
        }
    }
}

extern "C" void kernel_launch(void* const* d_in, const int* in_sizes, int n_in,
                              void* d_out, int out_size, void* d_ws, size_t ws_size,
                              hipStream_t stream) {
    const float* guided = (const float*)d_in[0];
    const float* x      = (const float*)d_in[1];
    const float* sparse = (const float*)d_in[2];
    float* out = (float*)d_out;

    dim3 blk(NT, 1, 1);
    dim3 grd((W + PTX - 1) / PTX, (H + PTY - 1) / PTY, BATCH);  // 7 x 4 x 8 = 224
    prop16_kernel<<<grd, blk, 0, stream>>>(guided, x, sparse, out);
}